// Round 11
// baseline (116.653 us; speedup 1.0000x reference)
//
#include <hip/hip_runtime.h>
#include <math.h>

// Problem constants: B=64, D=512, H=W=32 -> N=1024, NH=8, DH=64
#define BATCH  64
#define DCH    512
#define NPOS   1024
#define NH     8
#define NSPLIT 8                     // k_pv n-split (n-range 128 per block)
#define SCL    0.1803368801111244f   // 0.125 * log2(e): scores in exp2 domain

// ---------------------------------------------------------------------------
// K1 (prep): blocks 0-1: wqT[c*8+h] = SCL * sum_d q[h,d]*Wkv[c,h*64+d]
//            blocks 2-5: bias[h*1024+n] = SCL*(q.pe[n] + q.bkv)
// ---------------------------------------------------------------------------
__global__ __launch_bounds__(256) void k_prep(const float* __restrict__ q,
                                              const float* __restrict__ Wkv,
                                              const float* __restrict__ bkv,
                                              float* __restrict__ wqT,
                                              float* __restrict__ bias) {
    int blk = blockIdx.x;
    if (blk < 2) {
        int c = blk * 256 + threadIdx.x;
        const float4* wrow = (const float4*)(Wkv + (size_t)c * (2 * DCH));
        const float4* q4   = (const float4*)q;
        #pragma unroll
        for (int h = 0; h < NH; ++h) {
            float s = 0.f;
            #pragma unroll
            for (int d4 = 0; d4 < 16; ++d4) {
                float4 a = q4[h * 16 + d4];
                float4 w = wrow[h * 16 + d4];
                s = fmaf(a.x, w.x, fmaf(a.y, w.y, fmaf(a.z, w.z, fmaf(a.w, w.w, s))));
            }
            wqT[c * NH + h] = SCL * s;
        }
    } else {
        int n = (blk - 2) * 256 + threadIdx.x;
        float pq[NH];
        #pragma unroll
        for (int h = 0; h < NH; ++h) pq[h] = 0.f;
        const float kfac2 = -13.2877123795494f / 64.f;   // -log2(10000)/64
        for (int i = 0; i < 32; ++i) {
            float dt = exp2f((float)(2 * i) * kfac2);
            float ang = (float)n * dt;
            float sn, cs;
            sincosf(ang, &sn, &cs);
            #pragma unroll
            for (int h = 0; h < NH; ++h)
                pq[h] = fmaf(q[h * 64 + 2 * i], sn,
                        fmaf(q[h * 64 + 2 * i + 1], cs, pq[h]));
        }
        #pragma unroll
        for (int h = 0; h < NH; ++h) {
            float bq = 0.f;
            #pragma unroll 8
            for (int d = 0; d < 64; ++d)
                bq = fmaf(q[h * 64 + d], bkv[h * 64 + d], bq);
            bias[h * NPOS + n] = SCL * (pq[h] + bq);
        }
    }
}

// ---------------------------------------------------------------------------
// K2 (dots): pure HBM streamer. grid (16, B) = 1024 blocks, 512 thr (8 waves).
// lane = n (64-n tile), wave w owns c-stripe [w*64, w*64+64).
// x: coalesced 256B dword loads, rolling 8-deep window; weights: wave-uniform
// float4 loads (L1-hit after first touch). One barrier; raw scores out.
// ---------------------------------------------------------------------------
__global__ __launch_bounds__(512) void k_dots(const float* __restrict__ x,
                                              const float* __restrict__ wqT,
                                              const float* __restrict__ bias,
                                              float* __restrict__ dots) {
    __shared__ float sred[8][NH][64];   // 16 KB
    int b = blockIdx.y, nt = blockIdx.x;
    int t = threadIdx.x, w = t >> 6, lane = t & 63;
    int n0 = nt * 64, c0 = w * 64;

    float bv = bias[w * NPOS + n0 + lane];   // hoisted (used after barrier)

    const float* xp = x + ((size_t)b * DCH + c0) * NPOS + n0 + lane;
    const float* wr = wqT + c0 * NH;

    float acc[NH];
    #pragma unroll
    for (int h = 0; h < NH; ++h) acc[h] = 0.f;

    float xw[8];
    #pragma unroll
    for (int u = 0; u < 8; ++u) xw[u] = xp[(size_t)u * NPOS];

    #pragma unroll
    for (int k = 0; k < 64; ++k) {
        float xv = xw[k & 7];
        if (k < 56)   // refill slot -> constant 8 loads in flight
            xw[k & 7] = xp[(size_t)(k + 8) * NPOS];
        float wv[8];
        *(float4*)&wv[0] = *(const float4*)(wr + k * 8);
        *(float4*)&wv[4] = *(const float4*)(wr + k * 8 + 4);
        #pragma unroll
        for (int h = 0; h < NH; ++h)
            acc[h] = fmaf(xv, wv[h], acc[h]);
    }
    #pragma unroll
    for (int h = 0; h < NH; ++h) sred[w][h][lane] = acc[h];
    __syncthreads();

    // wave w finalizes head h = w
    float s = bv;
    #pragma unroll
    for (int o = 0; o < 8; ++o) s += sred[o][w][lane];
    dots[((size_t)b * NH + w) * NPOS + n0 + lane] = s;
}

// ---------------------------------------------------------------------------
// K3 (softmax): grid (B), 512 thr. Wave w = head w, full 1024-n row in-wave.
// Writes NORMALIZED attn (exp2 domain scores).
// ---------------------------------------------------------------------------
__global__ __launch_bounds__(512) void k_soft(const float* __restrict__ dots,
                                              float* __restrict__ attn) {
    int b = blockIdx.x, t = threadIdx.x, w = t >> 6, lane = t & 63;
    const float* p = dots + ((size_t)b * NH + w) * NPOS;
    float v[16], m = -1e30f;
    #pragma unroll
    for (int j = 0; j < 16; ++j) {
        v[j] = p[lane + 64 * j];
        m = fmaxf(m, v[j]);
    }
    #pragma unroll
    for (int o = 32; o; o >>= 1) m = fmaxf(m, __shfl_xor(m, o));
    float z = 0.f;
    #pragma unroll
    for (int j = 0; j < 16; ++j) { v[j] = exp2f(v[j] - m); z += v[j]; }
    #pragma unroll
    for (int o = 32; o; o >>= 1) z += __shfl_xor(z, o);
    float inv = 1.f / z;
    float* q = attn + ((size_t)b * NH + w) * NPOS;
    #pragma unroll
    for (int j = 0; j < 16; ++j) q[lane + 64 * j] = v[j] * inv;
}

// ---------------------------------------------------------------------------
// K4 (PV): grid (NSPLIT=8, B) = 512 blocks, 512 thr, 2 blocks/CU.
// x re-read comes from L3 (resident after k_dots). Wave w: c-stripe
// [w*64,w*64+64); thread (rg=lane>>2, nq=lane&3): 4 c x 4 n per j-step;
// attn staged 4 KB LDS; quad xor1/xor2 reduce; coalesced apart stores.
// ---------------------------------------------------------------------------
__global__ __launch_bounds__(512, 4) void k_pv(const float* __restrict__ x,
                                               const float* __restrict__ attn,
                                               float* __restrict__ apart) {  // [NSPLIT][B][NH][DCH]
    __shared__ float pls[NH][128];   // 4 KB
    int b = blockIdx.y, ns = blockIdx.x;
    int t = threadIdx.x, w = t >> 6, lane = t & 63;
    int n0 = ns * 128;

    if (t < 256) {   // stage attn[b][*][n0..n0+127]
        int h = t >> 5, i = t & 31;
        ((float4*)&pls[h][0])[i] =
            ((const float4*)(attn + ((size_t)b * NH + h) * NPOS + n0))[i];
    }
    __syncthreads();

    int rg = lane >> 2, nq = lane & 3;
    int c0 = w * 64;
    const float* xr = x + ((size_t)b * DCH + c0 + rg) * NPOS + n0 + nq * 4;

    float con[4][NH];
    #pragma unroll
    for (int cp = 0; cp < 4; ++cp)
        #pragma unroll
        for (int h = 0; h < NH; ++h) con[cp][h] = 0.f;

    #pragma unroll
    for (int j = 0; j < 8; ++j) {
        float4 xv[4];
        #pragma unroll
        for (int cp = 0; cp < 4; ++cp)
            xv[cp] = *(const float4*)(xr + (size_t)(cp * 16) * NPOS + j * 16);
        float4 pj[NH];
        #pragma unroll
        for (int h = 0; h < NH; ++h)
            pj[h] = *(const float4*)&pls[h][j * 16 + nq * 4];
        #pragma unroll
        for (int cp = 0; cp < 4; ++cp)
            #pragma unroll
            for (int h = 0; h < NH; ++h)
                con[cp][h] = fmaf(xv[cp].x, pj[h].x, fmaf(xv[cp].y, pj[h].y,
                             fmaf(xv[cp].z, pj[h].z, fmaf(xv[cp].w, pj[h].w, con[cp][h]))));
    }

    // reduce over nq (xor1, xor2 — quad_perm DPP) and store
    #pragma unroll
    for (int cp = 0; cp < 4; ++cp)
        #pragma unroll
        for (int h = 0; h < NH; ++h) {
            float v = con[cp][h];
            v += __shfl_xor(v, 1);
            v += __shfl_xor(v, 2);
            con[cp][h] = v;
        }

    size_t abase = ((size_t)ns * BATCH + b) * (NH * DCH);
    #pragma unroll
    for (int cp = 0; cp < 4; ++cp) {
        int c = c0 + cp * 16 + rg;
        float lo = (nq == 0) ? con[cp][0] : (nq == 1) ? con[cp][1]
                 : (nq == 2) ? con[cp][2] : con[cp][3];
        float hi = (nq == 0) ? con[cp][4] : (nq == 1) ? con[cp][5]
                 : (nq == 2) ? con[cp][6] : con[cp][7];
        apart[abase + (size_t)nq * DCH + c]       = lo;
        apart[abase + (size_t)(nq + 4) * DCH + c] = hi;
    }
}

// ---------------------------------------------------------------------------
// K5: sum NSPLIT partials + output GEMV. grid (B, 2), 512 threads.
// attn was pre-normalized, so no mz/scale factors at all.
// ---------------------------------------------------------------------------
__global__ __launch_bounds__(512) void k_comb(const float* __restrict__ apart,
                                              const float* __restrict__ Wkv,
                                              const float* __restrict__ bkv,
                                              float* __restrict__ out) {
    __shared__ float as[2048];       // 4 heads x 512 c (this half)
    __shared__ float red[2][256];
    int b = blockIdx.x, half = blockIdx.y, t = threadIdx.x;

    int e0 = t * 4;
    float v0 = 0.f, v1 = 0.f, v2 = 0.f, v3 = 0.f;
    #pragma unroll
    for (int j = 0; j < NSPLIT; ++j) {
        const float* src = apart + ((size_t)j * BATCH + b) * (NH * DCH)
                         + half * 2048 + e0;
        float4 lo = *(const float4*)src;
        v0 += lo.x; v1 += lo.y; v2 += lo.z; v3 += lo.w;
    }
    as[e0]     = v0;
    as[e0 + 1] = v1;
    as[e0 + 2] = v2;
    as[e0 + 3] = v3;
    __syncthreads();

    int o  = t & 255;
    int cp = t >> 8;
    int hd = half * 256 + o;                 // output column
    float a0 = 0.f, a1 = 0.f, a2 = 0.f, a3 = 0.f;
    const float* wp  = Wkv + DCH + hd;
    const float* apr = as + (o >> 6) * DCH;  // local head = o>>6
    int cbeg = cp * 256;
    #pragma unroll 4
    for (int c = cbeg; c < cbeg + 256; c += 4) {
        a0 = fmaf(apr[c],     wp[(size_t)c * (2 * DCH)],       a0);
        a1 = fmaf(apr[c + 1], wp[(size_t)(c + 1) * (2 * DCH)], a1);
        a2 = fmaf(apr[c + 2], wp[(size_t)(c + 2) * (2 * DCH)], a2);
        a3 = fmaf(apr[c + 3], wp[(size_t)(c + 3) * (2 * DCH)], a3);
    }
    red[cp][o] = (a0 + a1) + (a2 + a3);
    __syncthreads();
    if (t < 256) {
        int hd2 = half * 256 + t;
        out[(size_t)b * DCH + hd2] = bkv[DCH + hd2] + red[0][t] + red[1][t];
    }
}

// ---------------------------------------------------------------------------
extern "C" void kernel_launch(void* const* d_in, const int* in_sizes, int n_in,
                              void* d_out, int out_size, void* d_ws, size_t ws_size,
                              hipStream_t stream) {
    const float* x   = (const float*)d_in[0];   // (64, 512, 32, 32)
    const float* q   = (const float*)d_in[1];   // (1, 8, 1, 64)
    const float* Wkv = (const float*)d_in[2];   // (512, 1024)
    const float* bkv = (const float*)d_in[3];   // (1024,)
    float* out = (float*)d_out;                 // (64, 512)

    float* ws    = (float*)d_ws;
    float* wqT   = ws;                                         // 4 K floats
    float* bias  = wqT + DCH * NH;                             // 8 K
    float* dots  = bias + NH * NPOS;                           // 512 K (2 MB)
    float* attn  = dots + (size_t)BATCH * NH * NPOS;           // 512 K (2 MB)
    float* apart = attn + (size_t)BATCH * NH * NPOS;           // 2 M (8 MB)

    hipLaunchKernelGGL(k_prep, dim3(6),             dim3(256), 0, stream, q, Wkv, bkv, wqT, bias);
    hipLaunchKernelGGL(k_dots, dim3(16, BATCH),     dim3(512), 0, stream, x, wqT, bias, dots);
    hipLaunchKernelGGL(k_soft, dim3(BATCH),         dim3(512), 0, stream, dots, attn);
    hipLaunchKernelGGL(k_pv,   dim3(NSPLIT, BATCH), dim3(512), 0, stream, x, attn, apart);
    hipLaunchKernelGGL(k_comb, dim3(BATCH, 2),      dim3(512), 0, stream, apart, Wkv, bkv, out);
}

// Round 12
// 112.945 us; speedup vs baseline: 1.0328x; 1.0328x over previous
//
#include <hip/hip_runtime.h>
#include <math.h>

// Problem constants: B=64, D=512, H=W=32 -> N=1024, NH=8, DH=64
#define BATCH  64
#define DCH    512
#define NPOS   1024
#define NH     8
#define NSG    4       // output n-split groups
#define TPB    8       // n-tiles per block
#define NRANGE 32      // n per tile  (NSG*TPB*NRANGE == NPOS)

// ---------------------------------------------------------------------------
// K1 (prep): blocks 0-1: wqT[c*8+h] = 0.125 * sum_d q[h,d]*Wkv[c,h*64+d]
//            blocks 2-5: bias[h*1024+n] = 0.125*(q.pe[n] + q.bkv)
// ---------------------------------------------------------------------------
__global__ __launch_bounds__(256) void k_prep(const float* __restrict__ q,
                                              const float* __restrict__ Wkv,
                                              const float* __restrict__ bkv,
                                              float* __restrict__ wqT,
                                              float* __restrict__ bias) {
    int blk = blockIdx.x;
    if (blk < 2) {
        int c = blk * 256 + threadIdx.x;
        const float4* wrow = (const float4*)(Wkv + (size_t)c * (2 * DCH));
        const float4* q4   = (const float4*)q;
        #pragma unroll
        for (int h = 0; h < NH; ++h) {
            float s = 0.f;
            #pragma unroll
            for (int d4 = 0; d4 < 16; ++d4) {
                float4 a = q4[h * 16 + d4];
                float4 w = wrow[h * 16 + d4];
                s = fmaf(a.x, w.x, fmaf(a.y, w.y, fmaf(a.z, w.z, fmaf(a.w, w.w, s))));
            }
            wqT[c * NH + h] = 0.125f * s;
        }
    } else {
        int n = (blk - 2) * 256 + threadIdx.x;
        float pq[NH];
        #pragma unroll
        for (int h = 0; h < NH; ++h) pq[h] = 0.f;
        const float kfac2 = -13.2877123795494f / 64.f;   // -log2(10000)/64
        for (int i = 0; i < 32; ++i) {
            float dt = exp2f((float)(2 * i) * kfac2);
            float ang = (float)n * dt;
            float sn, cs;
            sincosf(ang, &sn, &cs);
            #pragma unroll
            for (int h = 0; h < NH; ++h)
                pq[h] = fmaf(q[h * 64 + 2 * i], sn,
                        fmaf(q[h * 64 + 2 * i + 1], cs, pq[h]));
        }
        #pragma unroll
        for (int h = 0; h < NH; ++h) {
            float bq = 0.f;
            #pragma unroll 8
            for (int d = 0; d < 64; ++d)
                bq = fmaf(q[h * 64 + d], bkv[h * 64 + d], bq);
            bias[h * NPOS + n] = 0.125f * (pq[h] + bq);
        }
    }
}

// ---------------------------------------------------------------------------
// K2 (flash, persistent x-in-regs): grid (NSG=4, B) = 256 blocks (1/CU),
// 512 threads, 1 block/CU (VGPR-limited by design, no launch cap -> no spill).
// Per tile tt (8 tiles of 32 n): load xv[8] (8 rows x 4 n per thread) ONCE;
// dots from xv + LDS wq; xor8/16/32 reduce; 32-lane softmax (fixed ref m=0);
// PV reuses the SAME xv registers. x is never re-read.
// ---------------------------------------------------------------------------
__global__ __launch_bounds__(512) void k_flash(const float* __restrict__ x,
                                               const float* __restrict__ wqT,
                                               const float* __restrict__ bias,
                                               float* __restrict__ apart,  // [NSG][B][NH][DCH]
                                               float* __restrict__ mz) {   // [NSG][B][16]
    __shared__ float wqs[DCH * NH];        // 16 KB
    __shared__ float sred[8][NH][NRANGE];  // 8 KB   [wave][h][n]
    __shared__ float pbuf[NH][NRANGE];     // 1 KB
    __shared__ float bls[NH][TPB * NRANGE]; // 8 KB  bias slice [h][256]

    int b = blockIdx.y, nsg = blockIdx.x;
    int t = threadIdx.x, w = t >> 6, lane = t & 63;
    int rg = lane >> 3, n8 = lane & 7;
    int c0 = w * 64;
    int nb = nsg * (TPB * NRANGE);

    {   // stage wq (16 KB) and bias slice (8 KB), coalesced
        const float4* s = (const float4*)wqT;
        float4* d = (float4*)wqs;
        d[t] = s[t]; d[t + 512] = s[t + 512];
        // bias[w][nb..nb+255] -> bls[w][0..255]; 4 floats per thread
        ((float4*)&bls[w][0])[lane] =
            *(const float4*)(bias + w * NPOS + nb + lane * 4);
    }
    __syncthreads();

    const float* gx = x + ((size_t)b * DCH + c0 + rg) * NPOS + nb + n8 * 4;

    float con[8][NH];                      // [k][h], 64 regs, accumulates over tiles
    #pragma unroll
    for (int k = 0; k < 8; ++k)
        #pragma unroll
        for (int h = 0; h < NH; ++h) con[k][h] = 0.f;
    float zl = 0.f;

    #pragma unroll 1
    for (int tt = 0; tt < TPB; ++tt) {
        // --- load this tile's x: 8 rows x 4 n per thread (32 regs) ---
        float4 xv[8];
        #pragma unroll
        for (int k = 0; k < 8; ++k)
            xv[k] = *(const float4*)(gx + (size_t)(8 * k) * NPOS + tt * NRANGE);

        // --- dots partials ---
        float acc[NH][4];
        #pragma unroll
        for (int h = 0; h < NH; ++h)
            #pragma unroll
            for (int e = 0; e < 4; ++e) acc[h][e] = 0.f;
        #pragma unroll
        for (int k = 0; k < 8; ++k) {
            int c = c0 + 8 * k + rg;
            float wv[8];
            *(float4*)&wv[0] = *(const float4*)&wqs[c * 8];
            *(float4*)&wv[4] = *(const float4*)&wqs[c * 8 + 4];
            #pragma unroll
            for (int h = 0; h < NH; ++h) {
                acc[h][0] = fmaf(xv[k].x, wv[h], acc[h][0]);
                acc[h][1] = fmaf(xv[k].y, wv[h], acc[h][1]);
                acc[h][2] = fmaf(xv[k].z, wv[h], acc[h][2]);
                acc[h][3] = fmaf(xv[k].w, wv[h], acc[h][3]);
            }
        }
        // butterfly over lane bits 3,4,5 (the 8 rg groups)
        #pragma unroll
        for (int h = 0; h < NH; ++h)
            #pragma unroll
            for (int e = 0; e < 4; ++e) {
                float v = acc[h][e];
                v += __shfl_xor(v, 8);
                v += __shfl_xor(v, 16);
                v += __shfl_xor(v, 32);
                acc[h][e] = v;
            }
        if (rg == 0) {
            #pragma unroll
            for (int h = 0; h < NH; ++h)
                *(float4*)&sred[w][h][n8 * 4] =
                    make_float4(acc[h][0], acc[h][1], acc[h][2], acc[h][3]);
        }
        __syncthreads();

        // --- softmax numerators (wave w = head w; lanes 0-31; fixed ref m=0)
        if (lane < 32) {
            float s = bls[w][tt * NRANGE + lane];
            #pragma unroll
            for (int o = 0; o < 8; ++o) s += sred[o][w][lane];
            float p = expf(s);
            zl += p;
            pbuf[w][lane] = p;
        }
        __syncthreads();

        // --- PV from the SAME xv registers ---
        float4 pj[NH];
        #pragma unroll
        for (int h = 0; h < NH; ++h)
            pj[h] = *(const float4*)&pbuf[h][n8 * 4];
        #pragma unroll
        for (int k = 0; k < 8; ++k)
            #pragma unroll
            for (int h = 0; h < NH; ++h)
                con[k][h] = fmaf(xv[k].x, pj[h].x, fmaf(xv[k].y, pj[h].y,
                            fmaf(xv[k].z, pj[h].z, fmaf(xv[k].w, pj[h].w, con[k][h]))));
    }

    // --- epilogue: reduce PV over n8 (lane bits 0-2), store apart ---
    size_t abase = ((size_t)nsg * BATCH + b) * (NH * DCH);
    #pragma unroll
    for (int k = 0; k < 8; ++k) {
        #pragma unroll
        for (int h = 0; h < NH; ++h) {
            float v = con[k][h];
            v += __shfl_xor(v, 1);
            v += __shfl_xor(v, 2);
            v += __shfl_xor(v, 4);
            con[k][h] = v;
        }
        float val = con[k][0];
        val = (n8 == 1) ? con[k][1] : val;
        val = (n8 == 2) ? con[k][2] : val;
        val = (n8 == 3) ? con[k][3] : val;
        val = (n8 == 4) ? con[k][4] : val;
        val = (n8 == 5) ? con[k][5] : val;
        val = (n8 == 6) ? con[k][6] : val;
        val = (n8 == 7) ? con[k][7] : val;
        apart[abase + (size_t)n8 * DCH + (c0 + 8 * k + rg)] = val;
    }
    // --- Z reduce (lanes 0-31 hold zl for head w) ---
    float zs = zl;
    zs += __shfl_xor(zs, 1);
    zs += __shfl_xor(zs, 2);
    zs += __shfl_xor(zs, 4);
    zs += __shfl_xor(zs, 8);
    zs += __shfl_xor(zs, 16);
    if (lane == 0) {
        float* mzp = mz + ((size_t)nsg * BATCH + b) * 2 * NH;
        mzp[w]      = 0.f;   // fixed reference max
        mzp[NH + w] = zs;
    }
}

// ---------------------------------------------------------------------------
// K3: combine NSG partials + output GEMV. grid (B, 2), 512 threads.
// ---------------------------------------------------------------------------
__global__ __launch_bounds__(512) void k_comb(const float* __restrict__ apart,
                                              const float* __restrict__ mz,
                                              const float* __restrict__ Wkv,
                                              const float* __restrict__ bkv,
                                              float* __restrict__ out) {
    __shared__ float as[NH * DCH];
    __shared__ float red[2][256];
    int b = blockIdx.x, half = blockIdx.y, t = threadIdx.x;
    int h = t >> 6;

    float M = -1e30f;
    #pragma unroll
    for (int j = 0; j < NSG; ++j)
        M = fmaxf(M, mz[((size_t)j * BATCH + b) * 2 * NH + h]);
    float Z = 0.f, fj[NSG];
    #pragma unroll
    for (int j = 0; j < NSG; ++j) {
        const float* mzp = mz + ((size_t)j * BATCH + b) * 2 * NH;
        fj[j] = expf(mzp[h] - M);
        Z = fmaf(fj[j], mzp[NH + h], Z);
    }
    float invZ = 1.f / Z;

    int e0 = t * 8;
    float v[8];
    #pragma unroll
    for (int k = 0; k < 8; ++k) v[k] = 0.f;
    #pragma unroll
    for (int j = 0; j < NSG; ++j) {
        const float* src = apart + ((size_t)j * BATCH + b) * (NH * DCH) + e0;
        float4 lo = *(const float4*)(src);
        float4 hi = *(const float4*)(src + 4);
        v[0] = fmaf(fj[j], lo.x, v[0]);
        v[1] = fmaf(fj[j], lo.y, v[1]);
        v[2] = fmaf(fj[j], lo.z, v[2]);
        v[3] = fmaf(fj[j], lo.w, v[3]);
        v[4] = fmaf(fj[j], hi.x, v[4]);
        v[5] = fmaf(fj[j], hi.y, v[5]);
        v[6] = fmaf(fj[j], hi.z, v[6]);
        v[7] = fmaf(fj[j], hi.w, v[7]);
    }
    #pragma unroll
    for (int k = 0; k < 8; ++k) as[e0 + k] = v[k] * invZ;
    __syncthreads();

    int o  = t & 255;
    int cp = t >> 8;
    int hd = half * 256 + o;
    int ho = hd >> 6;
    float a0 = 0.f, a1 = 0.f, a2 = 0.f, a3 = 0.f;
    const float* wp  = Wkv + DCH + hd;
    const float* apr = as + ho * DCH;
    int cbeg = cp * 256;
    #pragma unroll 4
    for (int c = cbeg; c < cbeg + 256; c += 4) {
        a0 = fmaf(apr[c],     wp[(size_t)c * (2 * DCH)],       a0);
        a1 = fmaf(apr[c + 1], wp[(size_t)(c + 1) * (2 * DCH)], a1);
        a2 = fmaf(apr[c + 2], wp[(size_t)(c + 2) * (2 * DCH)], a2);
        a3 = fmaf(apr[c + 3], wp[(size_t)(c + 3) * (2 * DCH)], a3);
    }
    red[cp][o] = (a0 + a1) + (a2 + a3);
    __syncthreads();
    if (t < 256) {
        int hd2 = half * 256 + t;
        out[(size_t)b * DCH + hd2] = bkv[DCH + hd2] + red[0][t] + red[1][t];
    }
}

// ---------------------------------------------------------------------------
extern "C" void kernel_launch(void* const* d_in, const int* in_sizes, int n_in,
                              void* d_out, int out_size, void* d_ws, size_t ws_size,
                              hipStream_t stream) {
    const float* x   = (const float*)d_in[0];   // (64, 512, 32, 32)
    const float* q   = (const float*)d_in[1];   // (1, 8, 1, 64)
    const float* Wkv = (const float*)d_in[2];   // (512, 1024)
    const float* bkv = (const float*)d_in[3];   // (1024,)
    float* out = (float*)d_out;                 // (64, 512)

    float* ws    = (float*)d_ws;
    float* wqT   = ws;                                      // 512*8
    float* bias  = wqT + DCH * NH;                          // 8*1024
    float* apart = bias + NH * NPOS;                        // 4*64*4096 = 4 MiB
    float* mz    = apart + (size_t)NSG * BATCH * NH * DCH;  // 4*64*16

    hipLaunchKernelGGL(k_prep,  dim3(6),           dim3(256), 0, stream, q, Wkv, bkv, wqT, bias);
    hipLaunchKernelGGL(k_flash, dim3(NSG, BATCH),  dim3(512), 0, stream, x, wqT, bias, apart, mz);
    hipLaunchKernelGGL(k_comb,  dim3(BATCH, 2),    dim3(512), 0, stream, apart, mz, Wkv, bkv, out);
}